// Round 1
// baseline (180.757 us; speedup 1.0000x reference)
//
#include <hip/hip_runtime.h>

// Reduction: mean(|convdata[:,:,3] - output[:,:,3]|)
// B=64, S=100, K=4, H=W=32. Channel-3 slice per (b,s) pair is a contiguous
// 1024-float (4 KB) chunk at offset (pair*4 + 3)*1024 floats.
// Total reduced elements: 64*100*1024 = 6,553,600.

#define RBLOCKS 1024
#define RTHREADS 256

__global__ __launch_bounds__(RTHREADS)
void absdiff_partial_kernel(const float4* __restrict__ outp,
                            const float4* __restrict__ conv,
                            float* __restrict__ partials,
                            int n4) {
    float acc = 0.0f;
    const int stride = gridDim.x * blockDim.x;
    for (int v = blockIdx.x * blockDim.x + threadIdx.x; v < n4; v += stride) {
        // v indexes float4s within the channel-3 subspace.
        // pair = v / 256 (256 float4 per 1024-float chunk)
        const int pair = v >> 8;
        const int within = v & 255;
        // global float4 index: pair * (4*1024/4) + 3*(1024/4) + within
        const size_t g = (size_t)pair * 1024 + 768 + (size_t)within;
        const float4 a = outp[g];
        const float4 b = conv[g];
        acc += fabsf(b.x - a.x) + fabsf(b.y - a.y)
             + fabsf(b.z - a.z) + fabsf(b.w - a.w);
    }
    // wave-64 shuffle reduction
    #pragma unroll
    for (int off = 32; off > 0; off >>= 1)
        acc += __shfl_down(acc, off, 64);
    __shared__ float smem[RTHREADS / 64];
    const int lane = threadIdx.x & 63;
    const int wave = threadIdx.x >> 6;
    if (lane == 0) smem[wave] = acc;
    __syncthreads();
    if (threadIdx.x == 0) {
        float s = 0.0f;
        #pragma unroll
        for (int w = 0; w < RTHREADS / 64; ++w) s += smem[w];
        partials[blockIdx.x] = s;
    }
}

__global__ __launch_bounds__(RTHREADS)
void final_reduce_kernel(const float* __restrict__ partials,
                         float* __restrict__ out,
                         int n, float inv_total) {
    float acc = 0.0f;
    for (int i = threadIdx.x; i < n; i += RTHREADS) acc += partials[i];
    #pragma unroll
    for (int off = 32; off > 0; off >>= 1)
        acc += __shfl_down(acc, off, 64);
    __shared__ float smem[RTHREADS / 64];
    const int lane = threadIdx.x & 63;
    const int wave = threadIdx.x >> 6;
    if (lane == 0) smem[wave] = acc;
    __syncthreads();
    if (threadIdx.x == 0) {
        float s = 0.0f;
        #pragma unroll
        for (int w = 0; w < RTHREADS / 64; ++w) s += smem[w];
        out[0] = s * inv_total;
    }
}

extern "C" void kernel_launch(void* const* d_in, const int* in_sizes, int n_in,
                              void* d_out, int out_size, void* d_ws, size_t ws_size,
                              hipStream_t stream) {
    const float4* outp = (const float4*)d_in[0];   // "output"
    const float4* conv = (const float4*)d_in[1];   // "convdata"
    float* partials = (float*)d_ws;                // RBLOCKS floats (4 KB)
    float* out = (float*)d_out;

    const int n_elems = 64 * 100 * 1024;           // 6,553,600
    const int n4 = n_elems / 4;                    // 1,638,400
    const float inv_total = 1.0f / (float)n_elems;

    absdiff_partial_kernel<<<RBLOCKS, RTHREADS, 0, stream>>>(outp, conv, partials, n4);
    final_reduce_kernel<<<1, RTHREADS, 0, stream>>>(partials, out, RBLOCKS, inv_total);
}